// Round 8
// baseline (275.427 us; speedup 1.0000x reference)
//
#include <hip/hip_runtime.h>

#define D_MODEL 128
#define EDGE_DIM 16

typedef __attribute__((ext_vector_type(8))) short bf16x8;
typedef __attribute__((ext_vector_type(4))) float f32x4;

__device__ __forceinline__ float sigmoid_fast(float a) {
    return 1.0f / (1.0f + __expf(-a));
}
__device__ __forceinline__ float gelu_tanh(float x) {
    float x2  = x * x;
    float arg = x * fmaf(0.07135481627f, x2, 1.59576912161f);
    return x * sigmoid_fast(arg);
}

// Polynomial GELU, valid |x| <= ~1.7 (hidden gate units: std 0.2, max ~1.2).
__device__ __forceinline__ float gelu_poly(float x) {
    float s = fminf(x * x, 2.89f);     // safety clamp at x=1.7
    float r = fmaf(-9.4447e-6f, s, 1.154347e-4f);
    r = fmaf(r, s, -1.1873282e-3f);
    r = fmaf(r, s, 9.9735570e-3f);
    r = fmaf(r, s, -6.64903801e-2f);
    r = fmaf(r, s, 3.989422804e-1f);
    return fmaf(s, r, 0.5f * x);
}

// float -> bf16, round-to-nearest-even (bit trick, ~4 VALU)
__device__ __forceinline__ unsigned short f2bf(float x) {
    unsigned u = __float_as_uint(x);
    u += 0x7FFFu + ((u >> 16) & 1u);
    return (unsigned short)(u >> 16);
}
// bf16 -> float (exact)
__device__ __forceinline__ float bf2f(unsigned short v) {
    return __uint_as_float((unsigned)v << 16);
}

// K0: cast x_src -> bf16 rows (xsb). Rationale: agg's random gather was
// 112 MB FETCH on 512B f32 rows; x_src's only downstream use is node's bf16
// A-fragment, so pre-rounding to bf16 halves gather bytes with no new
// precision class. 8 elems/thread, coalesced.
__global__ __launch_bounds__(256) void cast_kernel(
    const float* __restrict__ x, unsigned short* __restrict__ xb, int total8)
{
    int i = blockIdx.x * 256 + threadIdx.x;
    if (i >= total8) return;
    const float4* p = (const float4*)(x + (size_t)i * 8);
    float4 u0 = p[0], u1 = p[1];
    ushort4 o0, o1;
    o0.x = f2bf(u0.x); o0.y = f2bf(u0.y); o0.z = f2bf(u0.z); o0.w = f2bf(u0.w);
    o1.x = f2bf(u1.x); o1.y = f2bf(u1.y); o1.z = f2bf(u1.z); o1.w = f2bf(u1.w);
    ushort4* q = (ushort4*)(xb + (size_t)i * 8);
    q[0] = o0;
    q[1] = o1;
}

// K1: build wTfrag[kc][ft][lane][8] bf16 — per-lane B-fragment layout for
// mfma_f32_16x16x32_bf16 (verified R6). wT[d][f] = Wsrc[f][d] | Wdst[f][d-128].
__global__ __launch_bounds__(256) void wt_kernel(
    const float* __restrict__ Wsrc, const float* __restrict__ Wdst,
    unsigned short* __restrict__ wTfrag)
{
    int i = blockIdx.x * 256 + threadIdx.x;   // 0 .. 4095 (kc,ft,lane)
    if (i >= 8 * 8 * 64) return;
    int kc = i >> 9;          // 0..7  (K-chunk of 32)
    int ft = (i >> 6) & 7;    // 0..7  (f-tile of 16)
    int l  = i & 63;
    int f  = ft * 16 + (l & 15);
    int d0 = kc * 32 + (l >> 4) * 8;          // 8 consecutive d's
    const float* src = (d0 < D_MODEL) ? (Wsrc + (size_t)f * D_MODEL + d0)
                                      : (Wdst + (size_t)f * D_MODEL + (d0 - D_MODEL));
    unsigned short* dst = wTfrag + (size_t)i * 8;
#pragma unroll
    for (int v = 0; v < 8; v++) dst[v] = f2bf(src[v]);
}

// K2: histogram of edge destinations
__global__ __launch_bounds__(256) void hist_kernel(
    const int* __restrict__ edst, int* __restrict__ degi, int E)
{
    int e = blockIdx.x * 256 + threadIdx.x;
    if (e < E) atomicAdd(&degi[edst[e]], 1);
}

// K3a: per-block exclusive scan of degi (256/block), block totals to partials
__global__ __launch_bounds__(256) void scan1_kernel(
    const int* __restrict__ degi, int* __restrict__ starts,
    int* __restrict__ partials, int N)
{
    __shared__ int sm[256];
    int t = threadIdx.x;
    int idx = blockIdx.x * 256 + t;
    int val = (idx < N) ? degi[idx] : 0;
    sm[t] = val;
    __syncthreads();
#pragma unroll
    for (int off = 1; off < 256; off <<= 1) {
        int x = (t >= off) ? sm[t - off] : 0;
        __syncthreads();
        sm[t] += x;
        __syncthreads();
    }
    if (idx < N) starts[idx] = sm[t] - val;       // exclusive within block
    if (t == 255) partials[blockIdx.x] = sm[255]; // block total
}

// K3b: exclusive scan of block partials (single block, nblocks <= 256)
__global__ __launch_bounds__(256) void scan2_kernel(
    int* __restrict__ partials, int nblocks)
{
    __shared__ int sm[256];
    int t = threadIdx.x;
    int val = (t < nblocks) ? partials[t] : 0;
    sm[t] = val;
    __syncthreads();
#pragma unroll
    for (int off = 1; off < 256; off <<= 1) {
        int x = (t >= off) ? sm[t - off] : 0;
        __syncthreads();
        sm[t] += x;
        __syncthreads();
    }
    if (t < nblocks) partials[t] = sm[t] - val;   // exclusive
}

// K3c: add block offsets; duplicate into cursor
__global__ __launch_bounds__(256) void scan3_kernel(
    int* __restrict__ starts, int* __restrict__ cursor,
    const int* __restrict__ partials, int N)
{
    int idx = blockIdx.x * 256 + threadIdx.x;
    if (idx < N) {
        int s = starts[idx] + partials[idx >> 8];
        starts[idx] = s;
        cursor[idx] = s;
    }
}

// K4a: gate MLP via MFMA (verified R5/R6), compute-only; coalesced gate_out.
__global__ __launch_bounds__(256) void gate_kernel(
    const float* __restrict__ eattr,
    const float* __restrict__ gw1, const float* __restrict__ gb1,
    const float* __restrict__ gw2, const float* __restrict__ gb2,
    float* __restrict__ gate_out, int E)
{
    int lane = threadIdx.x & 63;
    int wid  = threadIdx.x >> 6;
    int col  = lane & 15;   // A-row / B-col / C-col within tile
    int half = lane >> 4;   // k-quarter (halves 0,1 hold d=0..15; 2,3 zero)

    bf16x8 bfrag[8];
    float  w2v[8], b1v[8];
#pragma unroll
    for (int jt = 0; jt < 8; jt++) {
        int j = jt * 16 + col;
        w2v[jt] = gw2[j];
        b1v[jt] = gb1[j];
        bf16x8 bf = {0, 0, 0, 0, 0, 0, 0, 0};
        if (half < 2) {
            const float4* wp = (const float4*)(gw1 + j * EDGE_DIM + half * 8);
            float4 u0 = wp[0], u1 = wp[1];
            bf[0] = (short)f2bf(u0.x); bf[1] = (short)f2bf(u0.y);
            bf[2] = (short)f2bf(u0.z); bf[3] = (short)f2bf(u0.w);
            bf[4] = (short)f2bf(u1.x); bf[5] = (short)f2bf(u1.y);
            bf[6] = (short)f2bf(u1.z); bf[7] = (short)f2bf(u1.w);
        }
        bfrag[jt] = bf;
    }
    float b2v = gb2[0];

    int ebase = blockIdx.x * 256 + wid * 64;
    float q[4] = {0.f, 0.f, 0.f, 0.f};   // per-group logit candidate (static idx)

#pragma unroll
    for (int g = 0; g < 4; g++) {
        int e0 = ebase + g * 16;
        if (e0 < E) {                    // wave-uniform guard
            int e = e0 + col;
            bf16x8 afrag = {0, 0, 0, 0, 0, 0, 0, 0};
            if (half < 2 && e < E) {
                const float4* ap = (const float4*)(eattr + (size_t)e * EDGE_DIM + half * 8);
                float4 a0 = ap[0], a1 = ap[1];
                afrag[0] = (short)f2bf(a0.x); afrag[1] = (short)f2bf(a0.y);
                afrag[2] = (short)f2bf(a0.z); afrag[3] = (short)f2bf(a0.w);
                afrag[4] = (short)f2bf(a1.x); afrag[5] = (short)f2bf(a1.y);
                afrag[6] = (short)f2bf(a1.z); afrag[7] = (short)f2bf(a1.w);
            }

            float p0 = 0.f, p1 = 0.f, p2 = 0.f, p3 = 0.f;
#pragma unroll
            for (int jt = 0; jt < 8; jt++) {
                f32x4 c = {0.f, 0.f, 0.f, 0.f};
                c = __builtin_amdgcn_mfma_f32_16x16x32_bf16(afrag, bfrag[jt], c, 0, 0, 0);
                p0 = fmaf(gelu_poly(c[0] + b1v[jt]), w2v[jt], p0);
                p1 = fmaf(gelu_poly(c[1] + b1v[jt]), w2v[jt], p1);
                p2 = fmaf(gelu_poly(c[2] + b1v[jt]), w2v[jt], p2);
                p3 = fmaf(gelu_poly(c[3] + b1v[jt]), w2v[jt], p3);
            }
#pragma unroll
            for (int m = 8; m >= 1; m >>= 1) {
                p0 += __shfl_xor(p0, m, 64);
                p1 += __shfl_xor(p1, m, 64);
                p2 += __shfl_xor(p2, m, 64);
                p3 += __shfl_xor(p3, m, 64);
            }
            int r3 = lane & 3;
            q[g] = (r3 == 0) ? p0 : (r3 == 1) ? p1 : (r3 == 2) ? p2 : p3;
        }
    }

    // redistribute: lane l takes group (l>>4)'s logit from lane ((l&15)>>2)*16+(l&3)
    int src = ((lane & 15) >> 2) * 16 + (lane & 3);
    float t0 = __shfl(q[0], src, 64);
    float t1 = __shfl(q[1], src, 64);
    float t2 = __shfl(q[2], src, 64);
    float t3 = __shfl(q[3], src, 64);
    int gsel = lane >> 4;
    float logit = (gsel == 0) ? t0 : (gsel == 1) ? t1 : (gsel == 2) ? t2 : t3;
    int e = ebase + lane;
    if (e < E) gate_out[e] = sigmoid_fast(logit + b2v);
}

// K4b: counting-sort scatter, 1 edge/thread; latency hidden by TLP.
__global__ __launch_bounds__(256) void scatter_kernel(
    const float* __restrict__ gate_out,
    const int* __restrict__ esrc, const int* __restrict__ edst,
    int* __restrict__ cursor,
    int* __restrict__ sorted_src, float* __restrict__ sorted_gate, int E)
{
    int e = blockIdx.x * 256 + threadIdx.x;
    if (e >= E) return;
    float g = gate_out[e];
    int  dv = edst[e];
    int  sv = esrc[e];
    int pos = atomicAdd(&cursor[dv], 1);
    sorted_src[pos]  = sv;
    sorted_gate[pos] = g;
}

// K5: segmented aggregation over bf16 x_src rows (256B/row, half the R7
// traffic), TWO nodes per wave, 4-edge unrolled -> up to 8 gathers in
// flight per wave. f32 accumulate; h written as bf16 (node's A-frag rounds
// to bf16 anyway, so no new precision class; saves 12.8MB wr + 12.8MB rd).
__global__ __launch_bounds__(256) void agg_kernel(
    const unsigned short* __restrict__ xsb,
    const int* __restrict__ sorted_src, const float* __restrict__ sorted_gate,
    const int* __restrict__ starts, const int* __restrict__ degi,
    unsigned short* __restrict__ hb, int N)
{
    int gid  = blockIdx.x * 256 + threadIdx.x;
    int wave = gid >> 6;
    int lane = gid & 63;
    int half = lane >> 5;       // which node of the pair
    int li   = lane & 31;       // dims li*4 .. li*4+3
    int n    = wave * 2 + half;
    if (n >= N) return;

    int begin = starts[n];
    int cnt   = degi[n];

    float a0 = 0.f, a1 = 0.f, a2 = 0.f, a3 = 0.f;
    int i = 0;
    for (; i + 4 <= cnt; i += 4) {
        int   sA = sorted_src[begin + i];
        int   sB = sorted_src[begin + i + 1];
        int   sC = sorted_src[begin + i + 2];
        int   sD = sorted_src[begin + i + 3];
        float gA = sorted_gate[begin + i];
        float gB = sorted_gate[begin + i + 1];
        float gC = sorted_gate[begin + i + 2];
        float gD = sorted_gate[begin + i + 3];
        ushort4 vA = ((const ushort4*)(xsb + (size_t)sA * D_MODEL))[li];
        ushort4 vB = ((const ushort4*)(xsb + (size_t)sB * D_MODEL))[li];
        ushort4 vC = ((const ushort4*)(xsb + (size_t)sC * D_MODEL))[li];
        ushort4 vD = ((const ushort4*)(xsb + (size_t)sD * D_MODEL))[li];
        a0 += gA * bf2f(vA.x) + gB * bf2f(vB.x) + gC * bf2f(vC.x) + gD * bf2f(vD.x);
        a1 += gA * bf2f(vA.y) + gB * bf2f(vB.y) + gC * bf2f(vC.y) + gD * bf2f(vD.y);
        a2 += gA * bf2f(vA.z) + gB * bf2f(vB.z) + gC * bf2f(vC.z) + gD * bf2f(vD.z);
        a3 += gA * bf2f(vA.w) + gB * bf2f(vB.w) + gC * bf2f(vC.w) + gD * bf2f(vD.w);
    }
    for (; i < cnt; i++) {
        int   s = sorted_src[begin + i];
        float g = sorted_gate[begin + i];
        ushort4 v = ((const ushort4*)(xsb + (size_t)s * D_MODEL))[li];
        a0 += g * bf2f(v.x);
        a1 += g * bf2f(v.y);
        a2 += g * bf2f(v.z);
        a3 += g * bf2f(v.w);
    }
    float r = 1.0f / (float)max(cnt, 1);
    ushort4 o;
    o.x = f2bf(a0 * r);
    o.y = f2bf(a1 * r);
    o.z = f2bf(a2 * r);
    o.w = f2bf(a3 * r);
    ((ushort4*)(hb + (size_t)n * D_MODEL))[li] = o;
}

// K6: out[n] = gelu(LN( [h | x_dst] @ wT + b )) via MFMA. LDS-free,
// barrier-free (verified R6). h is now bf16 -> A-frag for kc<4 is a direct
// 16B load (no conversion VALU); x_dst path (kc>=4) still converts f32.
#define NT 64    // nodes per block (4 waves x 16)

__global__ __launch_bounds__(256) void node_kernel(
    const unsigned short* __restrict__ hb,
    const float* __restrict__ x_dst, const unsigned short* __restrict__ wTfrag,
    const float* __restrict__ bdst, const float* __restrict__ gamma_,
    const float* __restrict__ beta_, float* __restrict__ out, int N)
{
    int lane = threadIdx.x & 63;
    int wid  = threadIdx.x >> 6;
    int col  = lane & 15;
    int half = lane >> 4;
    int base = blockIdx.x * NT + wid * 16;
    if (base >= N) return;                 // wave-uniform

    int arow = base + col;
    bool aok = arow < N;
    const unsigned short* hrow = hb + (size_t)arow * D_MODEL + half * 8;
    const float*          xrow = x_dst + (size_t)arow * D_MODEL + half * 8;

    f32x4 acc[8];
#pragma unroll
    for (int ft = 0; ft < 8; ft++) acc[ft] = (f32x4){0.f, 0.f, 0.f, 0.f};

    const bf16x8* bbase = ((const bf16x8*)wTfrag) + lane;

#pragma unroll
    for (int kc = 0; kc < 8; kc++) {
        bf16x8 afrag = {0, 0, 0, 0, 0, 0, 0, 0};
        if (aok) {
            if (kc < 4) {
                afrag = *(const bf16x8*)(hrow + kc * 32);   // direct bf16 load
            } else {
                const float* ap = xrow + (kc - 4) * 32;
                float4 a0 = ((const float4*)ap)[0];
                float4 a1 = ((const float4*)ap)[1];
                afrag[0] = (short)f2bf(a0.x); afrag[1] = (short)f2bf(a0.y);
                afrag[2] = (short)f2bf(a0.z); afrag[3] = (short)f2bf(a0.w);
                afrag[4] = (short)f2bf(a1.x); afrag[5] = (short)f2bf(a1.y);
                afrag[6] = (short)f2bf(a1.z); afrag[7] = (short)f2bf(a1.w);
            }
        }
        const bf16x8* bk = bbase + (size_t)kc * 512;   // 8 ft x 64 lanes
#pragma unroll
        for (int ft = 0; ft < 8; ft++) {
            bf16x8 bfrag = bk[ft * 64];
            acc[ft] = __builtin_amdgcn_mfma_f32_16x16x32_bf16(afrag, bfrag, acc[ft], 0, 0, 0);
        }
    }

    // epilogue: + b, LayerNorm over f (128 vals = 16-lane group x 8 regs), gelu
    float bv[8], gv[8], ev[8];
#pragma unroll
    for (int ft = 0; ft < 8; ft++) {
        int f = ft * 16 + col;
        bv[ft] = bdst[f];
        gv[ft] = gamma_[f];
        ev[ft] = beta_[f];
    }

#pragma unroll
    for (int r = 0; r < 4; r++) {
        int nr = base + half * 4 + r;      // C row = (lane>>4)*4 + reg
        float yv[8];
        float s1 = 0.f, s2 = 0.f;
#pragma unroll
        for (int ft = 0; ft < 8; ft++) {
            float x = acc[ft][r] + bv[ft];
            yv[ft] = x;
            s1 += x;
            s2 += x * x;
        }
#pragma unroll
        for (int m = 8; m >= 1; m >>= 1) {
            s1 += __shfl_xor(s1, m, 64);
            s2 += __shfl_xor(s2, m, 64);
        }
        float mu   = s1 * (1.0f / 128.0f);
        float var  = s2 * (1.0f / 128.0f) - mu * mu;
        float rstd = rsqrtf(var + 1e-5f);
        if (nr < N) {
            float* op = out + (size_t)nr * D_MODEL + col;
#pragma unroll
            for (int ft = 0; ft < 8; ft++)
                op[ft * 16] = gelu_tanh((yv[ft] - mu) * rstd * gv[ft] + ev[ft]);
        }
    }
}

extern "C" void kernel_launch(void* const* d_in, const int* in_sizes, int n_in,
                              void* d_out, int out_size, void* d_ws, size_t ws_size,
                              hipStream_t stream) {
    const float* x_src  = (const float*)d_in[0];
    const float* x_dst  = (const float*)d_in[1];
    const int*   esrc   = (const int*)d_in[2];
    const int*   edst   = (const int*)d_in[3];
    const float* eattr  = (const float*)d_in[4];
    const float* Wsrc   = (const float*)d_in[5];
    const float* Wdst   = (const float*)d_in[6];
    const float* bdst   = (const float*)d_in[7];
    const float* gw1    = (const float*)d_in[8];
    const float* gb1    = (const float*)d_in[9];
    const float* gw2    = (const float*)d_in[10];
    const float* gb2    = (const float*)d_in[11];
    const float* gamma_ = (const float*)d_in[12];
    const float* beta_  = (const float*)d_in[13];
    float* out = (float*)d_out;

    int E = in_sizes[2];
    int N = in_sizes[1] / D_MODEL;

    // workspace layout (bump-allocated, 256B aligned):
    char* ws = (char*)d_ws;
    size_t off = 0;
    auto alloc = [&](size_t bytes) {
        size_t cur = off;
        off = (off + bytes + 255) & ~(size_t)255;
        return (void*)(ws + cur);
    };
    unsigned short* wTfrag = (unsigned short*)alloc((size_t)8 * 8 * 64 * 8 * 2); // 64KB
    int*   degi        = (int*)  alloc((size_t)N * 4);
    int*   starts      = (int*)  alloc((size_t)N * 4);
    int*   cursor      = (int*)  alloc((size_t)N * 4);
    int*   partials    = (int*)  alloc(256 * 4);
    int*   sorted_src  = (int*)  alloc((size_t)E * 4);
    float* sorted_gate = (float*)alloc((size_t)E * 4);
    float* gate_out    = (float*)alloc((size_t)E * 4);
    unsigned short* xsb = (unsigned short*)alloc((size_t)N * D_MODEL * 2);  // 12.8MB
    unsigned short* hb  = (unsigned short*)alloc((size_t)N * D_MODEL * 2);  // 12.8MB

    int nblocksN = (N + 255) / 256;   // 196 for N=50000 (<=256 required by scan2)
    int nblocksE = (E + 255) / 256;
    int total8   = N * (D_MODEL / 8);               // 8-elem groups in x_src
    int nblocksC = (total8 + 255) / 256;

    hipMemsetAsync(degi, 0, (size_t)N * 4, stream);

    wt_kernel<<<16, 256, 0, stream>>>(Wsrc, Wdst, wTfrag);
    cast_kernel<<<nblocksC, 256, 0, stream>>>(x_src, xsb, total8);
    gate_kernel<<<nblocksE, 256, 0, stream>>>(
        eattr, gw1, gb1, gw2, gb2, gate_out, E);
    hist_kernel<<<nblocksE, 256, 0, stream>>>(edst, degi, E);
    scan1_kernel<<<nblocksN, 256, 0, stream>>>(degi, starts, partials, N);
    scan2_kernel<<<1, 256, 0, stream>>>(partials, nblocksN);
    scan3_kernel<<<nblocksN, 256, 0, stream>>>(starts, cursor, partials, N);
    scatter_kernel<<<nblocksE, 256, 0, stream>>>(
        gate_out, esrc, edst, cursor, sorted_src, sorted_gate, E);
    // two nodes per wave -> N*32 threads
    agg_kernel<<<((size_t)N * 32 + 255) / 256, 256, 0, stream>>>(
        xsb, sorted_src, sorted_gate, starts, degi, hb, N);
    node_kernel<<<(N + NT - 1) / NT, 256, 0, stream>>>(
        hb, x_dst, wTfrag, bdst, gamma_, beta_, out, N);
}

// Round 9
// 273.560 us; speedup vs baseline: 1.0068x; 1.0068x over previous
//
#include <hip/hip_runtime.h>

#define D_MODEL 128
#define EDGE_DIM 16

typedef __attribute__((ext_vector_type(8))) short bf16x8;
typedef __attribute__((ext_vector_type(4))) float f32x4;

__device__ __forceinline__ float sigmoid_fast(float a) {
    return 1.0f / (1.0f + __expf(-a));
}
__device__ __forceinline__ float gelu_tanh(float x) {
    float x2  = x * x;
    float arg = x * fmaf(0.07135481627f, x2, 1.59576912161f);
    return x * sigmoid_fast(arg);
}

// Polynomial GELU, valid |x| <= ~1.7 (hidden gate units: std 0.2, max ~1.2).
__device__ __forceinline__ float gelu_poly(float x) {
    float s = fminf(x * x, 2.89f);     // safety clamp at x=1.7
    float r = fmaf(-9.4447e-6f, s, 1.154347e-4f);
    r = fmaf(r, s, -1.1873282e-3f);
    r = fmaf(r, s, 9.9735570e-3f);
    r = fmaf(r, s, -6.64903801e-2f);
    r = fmaf(r, s, 3.989422804e-1f);
    return fmaf(s, r, 0.5f * x);
}

// float -> bf16, round-to-nearest-even (bit trick, ~4 VALU)
__device__ __forceinline__ unsigned short f2bf(float x) {
    unsigned u = __float_as_uint(x);
    u += 0x7FFFu + ((u >> 16) & 1u);
    return (unsigned short)(u >> 16);
}
// bf16 -> float (exact)
__device__ __forceinline__ float bf2f(unsigned short v) {
    return __uint_as_float((unsigned)v << 16);
}

// K0: cast x_src -> bf16 rows (xsb): halves agg's random-gather bytes (R8).
__global__ __launch_bounds__(256) void cast_kernel(
    const float* __restrict__ x, unsigned short* __restrict__ xb, int total8)
{
    int i = blockIdx.x * 256 + threadIdx.x;
    if (i >= total8) return;
    const float4* p = (const float4*)(x + (size_t)i * 8);
    float4 u0 = p[0], u1 = p[1];
    ushort4 o0, o1;
    o0.x = f2bf(u0.x); o0.y = f2bf(u0.y); o0.z = f2bf(u0.z); o0.w = f2bf(u0.w);
    o1.x = f2bf(u1.x); o1.y = f2bf(u1.y); o1.z = f2bf(u1.z); o1.w = f2bf(u1.w);
    ushort4* q = (ushort4*)(xb + (size_t)i * 8);
    q[0] = o0;
    q[1] = o1;
}

// K1: build wTfrag[kc][ft][lane][8] bf16 — per-lane B-fragment layout for
// mfma_f32_16x16x32_bf16 (verified R6). wT[d][f] = Wsrc[f][d] | Wdst[f][d-128].
__global__ __launch_bounds__(256) void wt_kernel(
    const float* __restrict__ Wsrc, const float* __restrict__ Wdst,
    unsigned short* __restrict__ wTfrag)
{
    int i = blockIdx.x * 256 + threadIdx.x;   // 0 .. 4095 (kc,ft,lane)
    if (i >= 8 * 8 * 64) return;
    int kc = i >> 9;          // 0..7  (K-chunk of 32)
    int ft = (i >> 6) & 7;    // 0..7  (f-tile of 16)
    int l  = i & 63;
    int f  = ft * 16 + (l & 15);
    int d0 = kc * 32 + (l >> 4) * 8;          // 8 consecutive d's
    const float* src = (d0 < D_MODEL) ? (Wsrc + (size_t)f * D_MODEL + d0)
                                      : (Wdst + (size_t)f * D_MODEL + (d0 - D_MODEL));
    unsigned short* dst = wTfrag + (size_t)i * 8;
#pragma unroll
    for (int v = 0; v < 8; v++) dst[v] = f2bf(src[v]);
}

// K2: histogram of edge destinations
__global__ __launch_bounds__(256) void hist_kernel(
    const int* __restrict__ edst, int* __restrict__ degi, int E)
{
    int e = blockIdx.x * 256 + threadIdx.x;
    if (e < E) atomicAdd(&degi[edst[e]], 1);
}

// K3a: per-block exclusive scan of degi (256/block), block totals to partials
__global__ __launch_bounds__(256) void scan1_kernel(
    const int* __restrict__ degi, int* __restrict__ starts,
    int* __restrict__ partials, int N)
{
    __shared__ int sm[256];
    int t = threadIdx.x;
    int idx = blockIdx.x * 256 + t;
    int val = (idx < N) ? degi[idx] : 0;
    sm[t] = val;
    __syncthreads();
#pragma unroll
    for (int off = 1; off < 256; off <<= 1) {
        int x = (t >= off) ? sm[t - off] : 0;
        __syncthreads();
        sm[t] += x;
        __syncthreads();
    }
    if (idx < N) starts[idx] = sm[t] - val;       // exclusive within block
    if (t == 255) partials[blockIdx.x] = sm[255]; // block total
}

// K3b: exclusive scan of block partials (single block, nblocks <= 256)
__global__ __launch_bounds__(256) void scan2_kernel(
    int* __restrict__ partials, int nblocks)
{
    __shared__ int sm[256];
    int t = threadIdx.x;
    int val = (t < nblocks) ? partials[t] : 0;
    sm[t] = val;
    __syncthreads();
#pragma unroll
    for (int off = 1; off < 256; off <<= 1) {
        int x = (t >= off) ? sm[t - off] : 0;
        __syncthreads();
        sm[t] += x;
        __syncthreads();
    }
    if (t < nblocks) partials[t] = sm[t] - val;   // exclusive
}

// K3c: add block offsets; duplicate into cursor
__global__ __launch_bounds__(256) void scan3_kernel(
    int* __restrict__ starts, int* __restrict__ cursor,
    const int* __restrict__ partials, int N)
{
    int idx = blockIdx.x * 256 + threadIdx.x;
    if (idx < N) {
        int s = starts[idx] + partials[idx >> 8];
        starts[idx] = s;
        cursor[idx] = s;
    }
}

// K4a: gate MLP via MFMA (math verified R5-R8), compute-only.
// R8 diagnosis: VGPR_Count=40 < live set (~55-60: bfrag 32 + w2/b1 16 + q 4
// + addr) -> compiler rematerialized the gw1 fragment loads inside each
// group, adding a dependent global-load stall before every MFMA cluster
// (latency-bound: VALUBusy 43%, MfmaUtil 2.6%, HBM 4%, occ 50%).
// Fix 1: __launch_bounds__(256,2) licenses ~128+ VGPR/wave (still 4
// waves/SIMD per m69) so bfrag stays resident.
// Fix 2: split each logit accumulator into two independent chains -> dep
// depth 8 -> 4 on the serial gelu->fma path.
__global__ __launch_bounds__(256, 2) void gate_kernel(
    const float* __restrict__ eattr,
    const float* __restrict__ gw1, const float* __restrict__ gb1,
    const float* __restrict__ gw2, const float* __restrict__ gb2,
    float* __restrict__ gate_out, int E)
{
    int lane = threadIdx.x & 63;
    int wid  = threadIdx.x >> 6;
    int col  = lane & 15;   // A-row / B-col / C-col within tile
    int half = lane >> 4;   // k-quarter (halves 0,1 hold d=0..15; 2,3 zero)

    bf16x8 bfrag[8];
    float  w2v[8], b1v[8];
#pragma unroll
    for (int jt = 0; jt < 8; jt++) {
        int j = jt * 16 + col;
        w2v[jt] = gw2[j];
        b1v[jt] = gb1[j];
        bf16x8 bf = {0, 0, 0, 0, 0, 0, 0, 0};
        if (half < 2) {
            const float4* wp = (const float4*)(gw1 + j * EDGE_DIM + half * 8);
            float4 u0 = wp[0], u1 = wp[1];
            bf[0] = (short)f2bf(u0.x); bf[1] = (short)f2bf(u0.y);
            bf[2] = (short)f2bf(u0.z); bf[3] = (short)f2bf(u0.w);
            bf[4] = (short)f2bf(u1.x); bf[5] = (short)f2bf(u1.y);
            bf[6] = (short)f2bf(u1.z); bf[7] = (short)f2bf(u1.w);
        }
        bfrag[jt] = bf;
    }
    float b2v = gb2[0];

    int ebase = blockIdx.x * 256 + wid * 64;
    float q[4] = {0.f, 0.f, 0.f, 0.f};   // per-group logit candidate (static idx)

#pragma unroll
    for (int g = 0; g < 4; g++) {
        int e0 = ebase + g * 16;
        if (e0 < E) {                    // wave-uniform guard
            int e = e0 + col;
            bf16x8 afrag = {0, 0, 0, 0, 0, 0, 0, 0};
            if (half < 2 && e < E) {
                const float4* ap = (const float4*)(eattr + (size_t)e * EDGE_DIM + half * 8);
                float4 a0 = ap[0], a1 = ap[1];
                afrag[0] = (short)f2bf(a0.x); afrag[1] = (short)f2bf(a0.y);
                afrag[2] = (short)f2bf(a0.z); afrag[3] = (short)f2bf(a0.w);
                afrag[4] = (short)f2bf(a1.x); afrag[5] = (short)f2bf(a1.y);
                afrag[6] = (short)f2bf(a1.z); afrag[7] = (short)f2bf(a1.w);
            }

            // two independent accumulator chains per C-row (halved dep depth)
            float p0a = 0.f, p0b = 0.f, p1a = 0.f, p1b = 0.f;
            float p2a = 0.f, p2b = 0.f, p3a = 0.f, p3b = 0.f;
#pragma unroll
            for (int jt = 0; jt < 8; jt += 2) {
                f32x4 ca = {0.f, 0.f, 0.f, 0.f};
                f32x4 cb = {0.f, 0.f, 0.f, 0.f};
                ca = __builtin_amdgcn_mfma_f32_16x16x32_bf16(afrag, bfrag[jt],     ca, 0, 0, 0);
                cb = __builtin_amdgcn_mfma_f32_16x16x32_bf16(afrag, bfrag[jt + 1], cb, 0, 0, 0);
                p0a = fmaf(gelu_poly(ca[0] + b1v[jt]),     w2v[jt],     p0a);
                p0b = fmaf(gelu_poly(cb[0] + b1v[jt + 1]), w2v[jt + 1], p0b);
                p1a = fmaf(gelu_poly(ca[1] + b1v[jt]),     w2v[jt],     p1a);
                p1b = fmaf(gelu_poly(cb[1] + b1v[jt + 1]), w2v[jt + 1], p1b);
                p2a = fmaf(gelu_poly(ca[2] + b1v[jt]),     w2v[jt],     p2a);
                p2b = fmaf(gelu_poly(cb[2] + b1v[jt + 1]), w2v[jt + 1], p2b);
                p3a = fmaf(gelu_poly(ca[3] + b1v[jt]),     w2v[jt],     p3a);
                p3b = fmaf(gelu_poly(cb[3] + b1v[jt + 1]), w2v[jt + 1], p3b);
            }
            float p0 = p0a + p0b, p1 = p1a + p1b;
            float p2 = p2a + p2b, p3 = p3a + p3b;
            // reduce across the 16-lane col-group (masks 1,2,4,8 stay inside it)
#pragma unroll
            for (int m = 8; m >= 1; m >>= 1) {
                p0 += __shfl_xor(p0, m, 64);
                p1 += __shfl_xor(p1, m, 64);
                p2 += __shfl_xor(p2, m, 64);
                p3 += __shfl_xor(p3, m, 64);
            }
            int r3 = lane & 3;
            q[g] = (r3 == 0) ? p0 : (r3 == 1) ? p1 : (r3 == 2) ? p2 : p3;
        }
    }

    // redistribute: lane l takes group (l>>4)'s logit from lane ((l&15)>>2)*16+(l&3)
    int src = ((lane & 15) >> 2) * 16 + (lane & 3);
    float t0 = __shfl(q[0], src, 64);
    float t1 = __shfl(q[1], src, 64);
    float t2 = __shfl(q[2], src, 64);
    float t3 = __shfl(q[3], src, 64);
    int gsel = lane >> 4;
    float logit = (gsel == 0) ? t0 : (gsel == 1) ? t1 : (gsel == 2) ? t2 : t3;
    int e = ebase + lane;
    if (e < E) gate_out[e] = sigmoid_fast(logit + b2v);
}

// K4b: counting-sort scatter, 1 edge/thread; latency hidden by TLP.
__global__ __launch_bounds__(256) void scatter_kernel(
    const float* __restrict__ gate_out,
    const int* __restrict__ esrc, const int* __restrict__ edst,
    int* __restrict__ cursor,
    int* __restrict__ sorted_src, float* __restrict__ sorted_gate, int E)
{
    int e = blockIdx.x * 256 + threadIdx.x;
    if (e >= E) return;
    float g = gate_out[e];
    int  dv = edst[e];
    int  sv = esrc[e];
    int pos = atomicAdd(&cursor[dv], 1);
    sorted_src[pos]  = sv;
    sorted_gate[pos] = g;
}

// K5: segmented aggregation over bf16 x_src rows (verified R8), TWO nodes
// per wave, 4-edge unrolled; f32 accumulate; h written as bf16.
__global__ __launch_bounds__(256) void agg_kernel(
    const unsigned short* __restrict__ xsb,
    const int* __restrict__ sorted_src, const float* __restrict__ sorted_gate,
    const int* __restrict__ starts, const int* __restrict__ degi,
    unsigned short* __restrict__ hb, int N)
{
    int gid  = blockIdx.x * 256 + threadIdx.x;
    int wave = gid >> 6;
    int lane = gid & 63;
    int half = lane >> 5;       // which node of the pair
    int li   = lane & 31;       // dims li*4 .. li*4+3
    int n    = wave * 2 + half;
    if (n >= N) return;

    int begin = starts[n];
    int cnt   = degi[n];

    float a0 = 0.f, a1 = 0.f, a2 = 0.f, a3 = 0.f;
    int i = 0;
    for (; i + 4 <= cnt; i += 4) {
        int   sA = sorted_src[begin + i];
        int   sB = sorted_src[begin + i + 1];
        int   sC = sorted_src[begin + i + 2];
        int   sD = sorted_src[begin + i + 3];
        float gA = sorted_gate[begin + i];
        float gB = sorted_gate[begin + i + 1];
        float gC = sorted_gate[begin + i + 2];
        float gD = sorted_gate[begin + i + 3];
        ushort4 vA = ((const ushort4*)(xsb + (size_t)sA * D_MODEL))[li];
        ushort4 vB = ((const ushort4*)(xsb + (size_t)sB * D_MODEL))[li];
        ushort4 vC = ((const ushort4*)(xsb + (size_t)sC * D_MODEL))[li];
        ushort4 vD = ((const ushort4*)(xsb + (size_t)sD * D_MODEL))[li];
        a0 += gA * bf2f(vA.x) + gB * bf2f(vB.x) + gC * bf2f(vC.x) + gD * bf2f(vD.x);
        a1 += gA * bf2f(vA.y) + gB * bf2f(vB.y) + gC * bf2f(vC.y) + gD * bf2f(vD.y);
        a2 += gA * bf2f(vA.z) + gB * bf2f(vB.z) + gC * bf2f(vC.z) + gD * bf2f(vD.z);
        a3 += gA * bf2f(vA.w) + gB * bf2f(vB.w) + gC * bf2f(vC.w) + gD * bf2f(vD.w);
    }
    for (; i < cnt; i++) {
        int   s = sorted_src[begin + i];
        float g = sorted_gate[begin + i];
        ushort4 v = ((const ushort4*)(xsb + (size_t)s * D_MODEL))[li];
        a0 += g * bf2f(v.x);
        a1 += g * bf2f(v.y);
        a2 += g * bf2f(v.z);
        a3 += g * bf2f(v.w);
    }
    float r = 1.0f / (float)max(cnt, 1);
    ushort4 o;
    o.x = f2bf(a0 * r);
    o.y = f2bf(a1 * r);
    o.z = f2bf(a2 * r);
    o.w = f2bf(a3 * r);
    ((ushort4*)(hb + (size_t)n * D_MODEL))[li] = o;
}

// K6: out[n] = gelu(LN( [h | x_dst] @ wT + b )) via MFMA. LDS-free,
// barrier-free (verified R6/R8).
#define NT 64    // nodes per block (4 waves x 16)

__global__ __launch_bounds__(256) void node_kernel(
    const unsigned short* __restrict__ hb,
    const float* __restrict__ x_dst, const unsigned short* __restrict__ wTfrag,
    const float* __restrict__ bdst, const float* __restrict__ gamma_,
    const float* __restrict__ beta_, float* __restrict__ out, int N)
{
    int lane = threadIdx.x & 63;
    int wid  = threadIdx.x >> 6;
    int col  = lane & 15;
    int half = lane >> 4;
    int base = blockIdx.x * NT + wid * 16;
    if (base >= N) return;                 // wave-uniform

    int arow = base + col;
    bool aok = arow < N;
    const unsigned short* hrow = hb + (size_t)arow * D_MODEL + half * 8;
    const float*          xrow = x_dst + (size_t)arow * D_MODEL + half * 8;

    f32x4 acc[8];
#pragma unroll
    for (int ft = 0; ft < 8; ft++) acc[ft] = (f32x4){0.f, 0.f, 0.f, 0.f};

    const bf16x8* bbase = ((const bf16x8*)wTfrag) + lane;

#pragma unroll
    for (int kc = 0; kc < 8; kc++) {
        bf16x8 afrag = {0, 0, 0, 0, 0, 0, 0, 0};
        if (aok) {
            if (kc < 4) {
                afrag = *(const bf16x8*)(hrow + kc * 32);   // direct bf16 load
            } else {
                const float* ap = xrow + (kc - 4) * 32;
                float4 a0 = ((const float4*)ap)[0];
                float4 a1 = ((const float4*)ap)[1];
                afrag[0] = (short)f2bf(a0.x); afrag[1] = (short)f2bf(a0.y);
                afrag[2] = (short)f2bf(a0.z); afrag[3] = (short)f2bf(a0.w);
                afrag[4] = (short)f2bf(a1.x); afrag[5] = (short)f2bf(a1.y);
                afrag[6] = (short)f2bf(a1.z); afrag[7] = (short)f2bf(a1.w);
            }
        }
        const bf16x8* bk = bbase + (size_t)kc * 512;   // 8 ft x 64 lanes
#pragma unroll
        for (int ft = 0; ft < 8; ft++) {
            bf16x8 bfrag = bk[ft * 64];
            acc[ft] = __builtin_amdgcn_mfma_f32_16x16x32_bf16(afrag, bfrag, acc[ft], 0, 0, 0);
        }
    }

    // epilogue: + b, LayerNorm over f (128 vals = 16-lane group x 8 regs), gelu
    float bv[8], gv[8], ev[8];
#pragma unroll
    for (int ft = 0; ft < 8; ft++) {
        int f = ft * 16 + col;
        bv[ft] = bdst[f];
        gv[ft] = gamma_[f];
        ev[ft] = beta_[f];
    }

#pragma unroll
    for (int r = 0; r < 4; r++) {
        int nr = base + half * 4 + r;      // C row = (lane>>4)*4 + reg
        float yv[8];
        float s1 = 0.f, s2 = 0.f;
#pragma unroll
        for (int ft = 0; ft < 8; ft++) {
            float x = acc[ft][r] + bv[ft];
            yv[ft] = x;
            s1 += x;
            s2 += x * x;
        }
#pragma unroll
        for (int m = 8; m >= 1; m >>= 1) {
            s1 += __shfl_xor(s1, m, 64);
            s2 += __shfl_xor(s2, m, 64);
        }
        float mu   = s1 * (1.0f / 128.0f);
        float var  = s2 * (1.0f / 128.0f) - mu * mu;
        float rstd = rsqrtf(var + 1e-5f);
        if (nr < N) {
            float* op = out + (size_t)nr * D_MODEL + col;
#pragma unroll
            for (int ft = 0; ft < 8; ft++)
                op[ft * 16] = gelu_tanh((yv[ft] - mu) * rstd * gv[ft] + ev[ft]);
        }
    }
}

extern "C" void kernel_launch(void* const* d_in, const int* in_sizes, int n_in,
                              void* d_out, int out_size, void* d_ws, size_t ws_size,
                              hipStream_t stream) {
    const float* x_src  = (const float*)d_in[0];
    const float* x_dst  = (const float*)d_in[1];
    const int*   esrc   = (const int*)d_in[2];
    const int*   edst   = (const int*)d_in[3];
    const float* eattr  = (const float*)d_in[4];
    const float* Wsrc   = (const float*)d_in[5];
    const float* Wdst   = (const float*)d_in[6];
    const float* bdst   = (const float*)d_in[7];
    const float* gw1    = (const float*)d_in[8];
    const float* gb1    = (const float*)d_in[9];
    const float* gw2    = (const float*)d_in[10];
    const float* gb2    = (const float*)d_in[11];
    const float* gamma_ = (const float*)d_in[12];
    const float* beta_  = (const float*)d_in[13];
    float* out = (float*)d_out;

    int E = in_sizes[2];
    int N = in_sizes[1] / D_MODEL;

    // workspace layout (bump-allocated, 256B aligned):
    char* ws = (char*)d_ws;
    size_t off = 0;
    auto alloc = [&](size_t bytes) {
        size_t cur = off;
        off = (off + bytes + 255) & ~(size_t)255;
        return (void*)(ws + cur);
    };
    unsigned short* wTfrag = (unsigned short*)alloc((size_t)8 * 8 * 64 * 8 * 2); // 64KB
    int*   degi        = (int*)  alloc((size_t)N * 4);
    int*   starts      = (int*)  alloc((size_t)N * 4);
    int*   cursor      = (int*)  alloc((size_t)N * 4);
    int*   partials    = (int*)  alloc(256 * 4);
    int*   sorted_src  = (int*)  alloc((size_t)E * 4);
    float* sorted_gate = (float*)alloc((size_t)E * 4);
    float* gate_out    = (float*)alloc((size_t)E * 4);
    unsigned short* xsb = (unsigned short*)alloc((size_t)N * D_MODEL * 2);  // 12.8MB
    unsigned short* hb  = (unsigned short*)alloc((size_t)N * D_MODEL * 2);  // 12.8MB

    int nblocksN = (N + 255) / 256;   // 196 for N=50000 (<=256 required by scan2)
    int nblocksE = (E + 255) / 256;
    int total8   = N * (D_MODEL / 8);               // 8-elem groups in x_src
    int nblocksC = (total8 + 255) / 256;

    hipMemsetAsync(degi, 0, (size_t)N * 4, stream);

    wt_kernel<<<16, 256, 0, stream>>>(Wsrc, Wdst, wTfrag);
    cast_kernel<<<nblocksC, 256, 0, stream>>>(x_src, xsb, total8);
    gate_kernel<<<nblocksE, 256, 0, stream>>>(
        eattr, gw1, gb1, gw2, gb2, gate_out, E);
    hist_kernel<<<nblocksE, 256, 0, stream>>>(edst, degi, E);
    scan1_kernel<<<nblocksN, 256, 0, stream>>>(degi, starts, partials, N);
    scan2_kernel<<<1, 256, 0, stream>>>(partials, nblocksN);
    scan3_kernel<<<nblocksN, 256, 0, stream>>>(starts, cursor, partials, N);
    scatter_kernel<<<nblocksE, 256, 0, stream>>>(
        gate_out, esrc, edst, cursor, sorted_src, sorted_gate, E);
    // two nodes per wave -> N*32 threads
    agg_kernel<<<((size_t)N * 32 + 255) / 256, 256, 0, stream>>>(
        xsb, sorted_src, sorted_gate, starts, degi, hb, N);
    node_kernel<<<(N + NT - 1) / NT, 256, 0, stream>>>(
        hb, x_dst, wTfrag, bdst, gamma_, beta_, out, N);
}

// Round 10
// 254.984 us; speedup vs baseline: 1.0802x; 1.0729x over previous
//
#include <hip/hip_runtime.h>

#define D_MODEL 128
#define EDGE_DIM 16

typedef __attribute__((ext_vector_type(8))) short bf16x8;
typedef __attribute__((ext_vector_type(4))) float f32x4;

__device__ __forceinline__ float sigmoid_fast(float a) {
    return 1.0f / (1.0f + __expf(-a));
}
__device__ __forceinline__ float gelu_tanh(float x) {
    float x2  = x * x;
    float arg = x * fmaf(0.07135481627f, x2, 1.59576912161f);
    return x * sigmoid_fast(arg);
}

// Polynomial GELU, valid |x| <= ~1.7 (hidden gate units: std 0.2, max ~1.2).
__device__ __forceinline__ float gelu_poly(float x) {
    float s = fminf(x * x, 2.89f);     // safety clamp at x=1.7
    float r = fmaf(-9.4447e-6f, s, 1.154347e-4f);
    r = fmaf(r, s, -1.1873282e-3f);
    r = fmaf(r, s, 9.9735570e-3f);
    r = fmaf(r, s, -6.64903801e-2f);
    r = fmaf(r, s, 3.989422804e-1f);
    return fmaf(s, r, 0.5f * x);
}

// float -> bf16, round-to-nearest-even (bit trick, ~4 VALU)
__device__ __forceinline__ unsigned short f2bf(float x) {
    unsigned u = __float_as_uint(x);
    u += 0x7FFFu + ((u >> 16) & 1u);
    return (unsigned short)(u >> 16);
}
// bf16 -> float (exact)
__device__ __forceinline__ float bf2f(unsigned short v) {
    return __uint_as_float((unsigned)v << 16);
}

// K1: fused prep — three independent domains in one dispatch (launch-gap
// reduction; R9 showed 12 serial dispatches with all user kernels <40us).
//  blocks [0, nbC):            cast x_src -> bf16 rows (xsb)       [R8-verified]
//  blocks [nbC, nbC+16):       build wTfrag B-fragments            [R6-verified]
//  blocks [nbC+16, ...):       histogram of edge destinations      [R0-verified]
__global__ __launch_bounds__(256) void prep_kernel(
    const float* __restrict__ Wsrc, const float* __restrict__ Wdst,
    unsigned short* __restrict__ wTfrag,
    const float* __restrict__ x, unsigned short* __restrict__ xb, int total8,
    const int* __restrict__ edst, int* __restrict__ degi, int E, int nbC)
{
    int bid = blockIdx.x;
    if (bid < nbC) {
        int i = bid * 256 + threadIdx.x;
        if (i < total8) {
            const float4* p = (const float4*)(x + (size_t)i * 8);
            float4 u0 = p[0], u1 = p[1];
            ushort4 o0, o1;
            o0.x = f2bf(u0.x); o0.y = f2bf(u0.y); o0.z = f2bf(u0.z); o0.w = f2bf(u0.w);
            o1.x = f2bf(u1.x); o1.y = f2bf(u1.y); o1.z = f2bf(u1.z); o1.w = f2bf(u1.w);
            ushort4* q = (ushort4*)(xb + (size_t)i * 8);
            q[0] = o0;
            q[1] = o1;
        }
    } else if (bid < nbC + 16) {
        int i = (bid - nbC) * 256 + threadIdx.x;   // 0 .. 4095 (kc,ft,lane)
        if (i < 8 * 8 * 64) {
            int kc = i >> 9;
            int ft = (i >> 6) & 7;
            int l  = i & 63;
            int f  = ft * 16 + (l & 15);
            int d0 = kc * 32 + (l >> 4) * 8;
            const float* src = (d0 < D_MODEL)
                ? (Wsrc + (size_t)f * D_MODEL + d0)
                : (Wdst + (size_t)f * D_MODEL + (d0 - D_MODEL));
            unsigned short* dst = wTfrag + (size_t)i * 8;
#pragma unroll
            for (int v = 0; v < 8; v++) dst[v] = f2bf(src[v]);
        }
    } else {
        int e = (bid - nbC - 16) * 256 + threadIdx.x;
        if (e < E) atomicAdd(&degi[edst[e]], 1);
    }
}

// K3a: per-block exclusive scan of degi (256/block), block totals to partials
__global__ __launch_bounds__(256) void scan1_kernel(
    const int* __restrict__ degi, int* __restrict__ starts,
    int* __restrict__ partials, int N)
{
    __shared__ int sm[256];
    int t = threadIdx.x;
    int idx = blockIdx.x * 256 + t;
    int val = (idx < N) ? degi[idx] : 0;
    sm[t] = val;
    __syncthreads();
#pragma unroll
    for (int off = 1; off < 256; off <<= 1) {
        int x = (t >= off) ? sm[t - off] : 0;
        __syncthreads();
        sm[t] += x;
        __syncthreads();
    }
    if (idx < N) starts[idx] = sm[t] - val;       // exclusive within block
    if (t == 255) partials[blockIdx.x] = sm[255]; // block total
}

// K3b: exclusive scan of block partials (single block, nblocks <= 256)
__global__ __launch_bounds__(256) void scan2_kernel(
    int* __restrict__ partials, int nblocks)
{
    __shared__ int sm[256];
    int t = threadIdx.x;
    int val = (t < nblocks) ? partials[t] : 0;
    sm[t] = val;
    __syncthreads();
#pragma unroll
    for (int off = 1; off < 256; off <<= 1) {
        int x = (t >= off) ? sm[t - off] : 0;
        __syncthreads();
        sm[t] += x;
        __syncthreads();
    }
    if (t < nblocks) partials[t] = sm[t] - val;   // exclusive
}

// K3c: add block offsets; duplicate into cursor
__global__ __launch_bounds__(256) void scan3_kernel(
    int* __restrict__ starts, int* __restrict__ cursor,
    const int* __restrict__ partials, int N)
{
    int idx = blockIdx.x * 256 + threadIdx.x;
    if (idx < N) {
        int s = starts[idx] + partials[idx >> 8];
        starts[idx] = s;
        cursor[idx] = s;
    }
}

// K4: gate MLP via MFMA + inline counting-sort scatter.
// Math verified R5-R9. Unlike R6's fused version (16 lanes serialized
// atomic+store per 16-edge group, 4x per wave, between compute phases),
// the redistribute epilogue leaves each of the 64 lanes holding its OWN
// edge's gate -> ONE fully-parallel atomic+store tail per wave, whose
// latency overlaps other waves' MFMA. Requires cursor ready (hist+scans
// run before this kernel). Eliminates scatter_kernel + gate_out pass.
__global__ __launch_bounds__(256, 2) void gate_scatter_kernel(
    const float* __restrict__ eattr,
    const float* __restrict__ gw1, const float* __restrict__ gb1,
    const float* __restrict__ gw2, const float* __restrict__ gb2,
    const int* __restrict__ esrc, const int* __restrict__ edst,
    int* __restrict__ cursor,
    int* __restrict__ sorted_src, float* __restrict__ sorted_gate, int E)
{
    int lane = threadIdx.x & 63;
    int wid  = threadIdx.x >> 6;
    int col  = lane & 15;   // A-row / B-col / C-col within tile
    int half = lane >> 4;   // k-quarter (halves 0,1 hold d=0..15; 2,3 zero)

    bf16x8 bfrag[8];
    float  w2v[8], b1v[8];
#pragma unroll
    for (int jt = 0; jt < 8; jt++) {
        int j = jt * 16 + col;
        w2v[jt] = gw2[j];
        b1v[jt] = gb1[j];
        bf16x8 bf = {0, 0, 0, 0, 0, 0, 0, 0};
        if (half < 2) {
            const float4* wp = (const float4*)(gw1 + j * EDGE_DIM + half * 8);
            float4 u0 = wp[0], u1 = wp[1];
            bf[0] = (short)f2bf(u0.x); bf[1] = (short)f2bf(u0.y);
            bf[2] = (short)f2bf(u0.z); bf[3] = (short)f2bf(u0.w);
            bf[4] = (short)f2bf(u1.x); bf[5] = (short)f2bf(u1.y);
            bf[6] = (short)f2bf(u1.z); bf[7] = (short)f2bf(u1.w);
        }
        bfrag[jt] = bf;
    }
    float b2v = gb2[0];

    int ebase = blockIdx.x * 256 + wid * 64;
    float q[4] = {0.f, 0.f, 0.f, 0.f};   // per-group logit candidate (static idx)

#pragma unroll
    for (int g = 0; g < 4; g++) {
        int e0 = ebase + g * 16;
        if (e0 < E) {                    // wave-uniform guard
            int e = e0 + col;
            bf16x8 afrag = {0, 0, 0, 0, 0, 0, 0, 0};
            if (half < 2 && e < E) {
                const float4* ap = (const float4*)(eattr + (size_t)e * EDGE_DIM + half * 8);
                float4 a0 = ap[0], a1 = ap[1];
                afrag[0] = (short)f2bf(a0.x); afrag[1] = (short)f2bf(a0.y);
                afrag[2] = (short)f2bf(a0.z); afrag[3] = (short)f2bf(a0.w);
                afrag[4] = (short)f2bf(a1.x); afrag[5] = (short)f2bf(a1.y);
                afrag[6] = (short)f2bf(a1.z); afrag[7] = (short)f2bf(a1.w);
            }

            // two independent accumulator chains per C-row (halved dep depth)
            float p0a = 0.f, p0b = 0.f, p1a = 0.f, p1b = 0.f;
            float p2a = 0.f, p2b = 0.f, p3a = 0.f, p3b = 0.f;
#pragma unroll
            for (int jt = 0; jt < 8; jt += 2) {
                f32x4 ca = {0.f, 0.f, 0.f, 0.f};
                f32x4 cb = {0.f, 0.f, 0.f, 0.f};
                ca = __builtin_amdgcn_mfma_f32_16x16x32_bf16(afrag, bfrag[jt],     ca, 0, 0, 0);
                cb = __builtin_amdgcn_mfma_f32_16x16x32_bf16(afrag, bfrag[jt + 1], cb, 0, 0, 0);
                p0a = fmaf(gelu_poly(ca[0] + b1v[jt]),     w2v[jt],     p0a);
                p0b = fmaf(gelu_poly(cb[0] + b1v[jt + 1]), w2v[jt + 1], p0b);
                p1a = fmaf(gelu_poly(ca[1] + b1v[jt]),     w2v[jt],     p1a);
                p1b = fmaf(gelu_poly(cb[1] + b1v[jt + 1]), w2v[jt + 1], p1b);
                p2a = fmaf(gelu_poly(ca[2] + b1v[jt]),     w2v[jt],     p2a);
                p2b = fmaf(gelu_poly(cb[2] + b1v[jt + 1]), w2v[jt + 1], p2b);
                p3a = fmaf(gelu_poly(ca[3] + b1v[jt]),     w2v[jt],     p3a);
                p3b = fmaf(gelu_poly(cb[3] + b1v[jt + 1]), w2v[jt + 1], p3b);
            }
            float p0 = p0a + p0b, p1 = p1a + p1b;
            float p2 = p2a + p2b, p3 = p3a + p3b;
            // reduce across the 16-lane col-group (masks 1,2,4,8 stay inside it)
#pragma unroll
            for (int m = 8; m >= 1; m >>= 1) {
                p0 += __shfl_xor(p0, m, 64);
                p1 += __shfl_xor(p1, m, 64);
                p2 += __shfl_xor(p2, m, 64);
                p3 += __shfl_xor(p3, m, 64);
            }
            int r3 = lane & 3;
            q[g] = (r3 == 0) ? p0 : (r3 == 1) ? p1 : (r3 == 2) ? p2 : p3;
        }
    }

    // redistribute: lane l takes group (l>>4)'s logit from lane ((l&15)>>2)*16+(l&3)
    int src = ((lane & 15) >> 2) * 16 + (lane & 3);
    float t0 = __shfl(q[0], src, 64);
    float t1 = __shfl(q[1], src, 64);
    float t2 = __shfl(q[2], src, 64);
    float t3 = __shfl(q[3], src, 64);
    int gsel = lane >> 4;
    float logit = (gsel == 0) ? t0 : (gsel == 1) ? t1 : (gsel == 2) ? t2 : t3;

    // inline scatter: all 64 lanes in parallel, once per wave
    int e = ebase + lane;
    if (e < E) {
        float gt = sigmoid_fast(logit + b2v);
        int dv = edst[e];            // coalesced
        int sv = esrc[e];            // coalesced
        int pos = atomicAdd(&cursor[dv], 1);
        sorted_src[pos]  = sv;
        sorted_gate[pos] = gt;
    }
}

// K5: segmented aggregation over bf16 x_src rows (verified R8), TWO nodes
// per wave, 4-edge unrolled; f32 accumulate; h written as bf16.
__global__ __launch_bounds__(256) void agg_kernel(
    const unsigned short* __restrict__ xsb,
    const int* __restrict__ sorted_src, const float* __restrict__ sorted_gate,
    const int* __restrict__ starts, const int* __restrict__ degi,
    unsigned short* __restrict__ hb, int N)
{
    int gid  = blockIdx.x * 256 + threadIdx.x;
    int wave = gid >> 6;
    int lane = gid & 63;
    int half = lane >> 5;       // which node of the pair
    int li   = lane & 31;       // dims li*4 .. li*4+3
    int n    = wave * 2 + half;
    if (n >= N) return;

    int begin = starts[n];
    int cnt   = degi[n];

    float a0 = 0.f, a1 = 0.f, a2 = 0.f, a3 = 0.f;
    int i = 0;
    for (; i + 4 <= cnt; i += 4) {
        int   sA = sorted_src[begin + i];
        int   sB = sorted_src[begin + i + 1];
        int   sC = sorted_src[begin + i + 2];
        int   sD = sorted_src[begin + i + 3];
        float gA = sorted_gate[begin + i];
        float gB = sorted_gate[begin + i + 1];
        float gC = sorted_gate[begin + i + 2];
        float gD = sorted_gate[begin + i + 3];
        ushort4 vA = ((const ushort4*)(xsb + (size_t)sA * D_MODEL))[li];
        ushort4 vB = ((const ushort4*)(xsb + (size_t)sB * D_MODEL))[li];
        ushort4 vC = ((const ushort4*)(xsb + (size_t)sC * D_MODEL))[li];
        ushort4 vD = ((const ushort4*)(xsb + (size_t)sD * D_MODEL))[li];
        a0 += gA * bf2f(vA.x) + gB * bf2f(vB.x) + gC * bf2f(vC.x) + gD * bf2f(vD.x);
        a1 += gA * bf2f(vA.y) + gB * bf2f(vB.y) + gC * bf2f(vC.y) + gD * bf2f(vD.y);
        a2 += gA * bf2f(vA.z) + gB * bf2f(vB.z) + gC * bf2f(vC.z) + gD * bf2f(vD.z);
        a3 += gA * bf2f(vA.w) + gB * bf2f(vB.w) + gC * bf2f(vC.w) + gD * bf2f(vD.w);
    }
    for (; i < cnt; i++) {
        int   s = sorted_src[begin + i];
        float g = sorted_gate[begin + i];
        ushort4 v = ((const ushort4*)(xsb + (size_t)s * D_MODEL))[li];
        a0 += g * bf2f(v.x);
        a1 += g * bf2f(v.y);
        a2 += g * bf2f(v.z);
        a3 += g * bf2f(v.w);
    }
    float r = 1.0f / (float)max(cnt, 1);
    ushort4 o;
    o.x = f2bf(a0 * r);
    o.y = f2bf(a1 * r);
    o.z = f2bf(a2 * r);
    o.w = f2bf(a3 * r);
    ((ushort4*)(hb + (size_t)n * D_MODEL))[li] = o;
}

// K6: out[n] = gelu(LN( [h | x_dst] @ wT + b )) via MFMA. LDS-free,
// barrier-free (verified R6/R8).
#define NT 64    // nodes per block (4 waves x 16)

__global__ __launch_bounds__(256) void node_kernel(
    const unsigned short* __restrict__ hb,
    const float* __restrict__ x_dst, const unsigned short* __restrict__ wTfrag,
    const float* __restrict__ bdst, const float* __restrict__ gamma_,
    const float* __restrict__ beta_, float* __restrict__ out, int N)
{
    int lane = threadIdx.x & 63;
    int wid  = threadIdx.x >> 6;
    int col  = lane & 15;
    int half = lane >> 4;
    int base = blockIdx.x * NT + wid * 16;
    if (base >= N) return;                 // wave-uniform

    int arow = base + col;
    bool aok = arow < N;
    const unsigned short* hrow = hb + (size_t)arow * D_MODEL + half * 8;
    const float*          xrow = x_dst + (size_t)arow * D_MODEL + half * 8;

    f32x4 acc[8];
#pragma unroll
    for (int ft = 0; ft < 8; ft++) acc[ft] = (f32x4){0.f, 0.f, 0.f, 0.f};

    const bf16x8* bbase = ((const bf16x8*)wTfrag) + lane;

#pragma unroll
    for (int kc = 0; kc < 8; kc++) {
        bf16x8 afrag = {0, 0, 0, 0, 0, 0, 0, 0};
        if (aok) {
            if (kc < 4) {
                afrag = *(const bf16x8*)(hrow + kc * 32);   // direct bf16 load
            } else {
                const float* ap = xrow + (kc - 4) * 32;
                float4 a0 = ((const float4*)ap)[0];
                float4 a1 = ((const float4*)ap)[1];
                afrag[0] = (short)f2bf(a0.x); afrag[1] = (short)f2bf(a0.y);
                afrag[2] = (short)f2bf(a0.z); afrag[3] = (short)f2bf(a0.w);
                afrag[4] = (short)f2bf(a1.x); afrag[5] = (short)f2bf(a1.y);
                afrag[6] = (short)f2bf(a1.z); afrag[7] = (short)f2bf(a1.w);
            }
        }
        const bf16x8* bk = bbase + (size_t)kc * 512;   // 8 ft x 64 lanes
#pragma unroll
        for (int ft = 0; ft < 8; ft++) {
            bf16x8 bfrag = bk[ft * 64];
            acc[ft] = __builtin_amdgcn_mfma_f32_16x16x32_bf16(afrag, bfrag, acc[ft], 0, 0, 0);
        }
    }

    // epilogue: + b, LayerNorm over f (128 vals = 16-lane group x 8 regs), gelu
    float bv[8], gv[8], ev[8];
#pragma unroll
    for (int ft = 0; ft < 8; ft++) {
        int f = ft * 16 + col;
        bv[ft] = bdst[f];
        gv[ft] = gamma_[f];
        ev[ft] = beta_[f];
    }

#pragma unroll
    for (int r = 0; r < 4; r++) {
        int nr = base + half * 4 + r;      // C row = (lane>>4)*4 + reg
        float yv[8];
        float s1 = 0.f, s2 = 0.f;
#pragma unroll
        for (int ft = 0; ft < 8; ft++) {
            float x = acc[ft][r] + bv[ft];
            yv[ft] = x;
            s1 += x;
            s2 += x * x;
        }
#pragma unroll
        for (int m = 8; m >= 1; m >>= 1) {
            s1 += __shfl_xor(s1, m, 64);
            s2 += __shfl_xor(s2, m, 64);
        }
        float mu   = s1 * (1.0f / 128.0f);
        float var  = s2 * (1.0f / 128.0f) - mu * mu;
        float rstd = rsqrtf(var + 1e-5f);
        if (nr < N) {
            float* op = out + (size_t)nr * D_MODEL + col;
#pragma unroll
            for (int ft = 0; ft < 8; ft++)
                op[ft * 16] = gelu_tanh((yv[ft] - mu) * rstd * gv[ft] + ev[ft]);
        }
    }
}

extern "C" void kernel_launch(void* const* d_in, const int* in_sizes, int n_in,
                              void* d_out, int out_size, void* d_ws, size_t ws_size,
                              hipStream_t stream) {
    const float* x_src  = (const float*)d_in[0];
    const float* x_dst  = (const float*)d_in[1];
    const int*   esrc   = (const int*)d_in[2];
    const int*   edst   = (const int*)d_in[3];
    const float* eattr  = (const float*)d_in[4];
    const float* Wsrc   = (const float*)d_in[5];
    const float* Wdst   = (const float*)d_in[6];
    const float* bdst   = (const float*)d_in[7];
    const float* gw1    = (const float*)d_in[8];
    const float* gb1    = (const float*)d_in[9];
    const float* gw2    = (const float*)d_in[10];
    const float* gb2    = (const float*)d_in[11];
    const float* gamma_ = (const float*)d_in[12];
    const float* beta_  = (const float*)d_in[13];
    float* out = (float*)d_out;

    int E = in_sizes[2];
    int N = in_sizes[1] / D_MODEL;

    // workspace layout (bump-allocated, 256B aligned):
    char* ws = (char*)d_ws;
    size_t off = 0;
    auto alloc = [&](size_t bytes) {
        size_t cur = off;
        off = (off + bytes + 255) & ~(size_t)255;
        return (void*)(ws + cur);
    };
    unsigned short* wTfrag = (unsigned short*)alloc((size_t)8 * 8 * 64 * 8 * 2); // 64KB
    int*   degi        = (int*)  alloc((size_t)N * 4);
    int*   starts      = (int*)  alloc((size_t)N * 4);
    int*   cursor      = (int*)  alloc((size_t)N * 4);
    int*   partials    = (int*)  alloc(256 * 4);
    int*   sorted_src  = (int*)  alloc((size_t)E * 4);
    float* sorted_gate = (float*)alloc((size_t)E * 4);
    unsigned short* xsb = (unsigned short*)alloc((size_t)N * D_MODEL * 2);  // 12.8MB
    unsigned short* hb  = (unsigned short*)alloc((size_t)N * D_MODEL * 2);  // 12.8MB

    int nblocksN = (N + 255) / 256;   // 196 for N=50000 (<=256 required by scan2)
    int nblocksE = (E + 255) / 256;
    int total8   = N * (D_MODEL / 8);               // 8-elem groups in x_src
    int nblocksC = (total8 + 255) / 256;

    hipMemsetAsync(degi, 0, (size_t)N * 4, stream);

    // fused wt + cast + hist (disjoint block ranges)
    prep_kernel<<<nblocksC + 16 + nblocksE, 256, 0, stream>>>(
        Wsrc, Wdst, wTfrag, x_src, xsb, total8, edst, degi, E, nblocksC);
    scan1_kernel<<<nblocksN, 256, 0, stream>>>(degi, starts, partials, N);
    scan2_kernel<<<1, 256, 0, stream>>>(partials, nblocksN);
    scan3_kernel<<<nblocksN, 256, 0, stream>>>(starts, cursor, partials, N);
    // gate MLP + inline scatter (cursor ready)
    gate_scatter_kernel<<<nblocksE, 256, 0, stream>>>(
        eattr, gw1, gb1, gw2, gb2, esrc, edst, cursor, sorted_src, sorted_gate, E);
    // two nodes per wave -> N*32 threads
    agg_kernel<<<((size_t)N * 32 + 255) / 256, 256, 0, stream>>>(
        xsb, sorted_src, sorted_gate, starts, degi, hb, N);
    node_kernel<<<(N + NT - 1) / NT, 256, 0, stream>>>(
        hb, x_dst, wTfrag, bdst, gamma_, beta_, out, N);
}